// Round 2
// baseline (1369.083 us; speedup 1.0000x reference)
//
#include <hip/hip_runtime.h>
#include <hip/hip_bf16.h>
#include <cstdint>

typedef __bf16 bf16;
typedef __bf16 bf16x4 __attribute__((ext_vector_type(4)));
typedef __bf16 bf16x8 __attribute__((ext_vector_type(8)));
typedef float  f32x4  __attribute__((ext_vector_type(4)));

#define BTOK 8192
#define FDIM 2048
#define NEXP 16
#define UDIM 2048
#define DMODEL 2048
#define BSTRIDE 8320  // bucket capacity per expert (8192 + 128 pad)

__device__ __forceinline__ void gl2lds16(const void* g, void* l) {
  __builtin_amdgcn_global_load_lds(
      (const __attribute__((address_space(1))) void*)g,
      (__attribute__((address_space(3))) void*)l, 16, 0, 0);
}

// ---------- shared GEMM core: 128x128 tile, BK=32, 256 thr, 16x16x32 bf16 MFMA ----------
__device__ __forceinline__ void gemm_core(
    const bf16* __restrict__ aP0, const bf16* __restrict__ aP1,
    const bf16* __restrict__ bP0, const bf16* __restrict__ bP1,
    int Kdim, bf16* As, bf16* Bs, f32x4 acc[4][4])
{
  const int tid  = threadIdx.x;
  const int lane = tid & 63;
  const int wave = tid >> 6;
  const int wm   = (wave >> 1) * 64;
  const int wn   = (wave & 1) * 64;
  const int lhi  = lane >> 4;
  const int llo  = lane & 15;
  bf16* lA0 = As + wave * 512;
  bf16* lA1 = As + 2048 + wave * 512;
  bf16* lB0 = Bs + wave * 512;
  bf16* lB1 = Bs + 2048 + wave * 512;
  for (int k0 = 0; k0 < Kdim; k0 += 32) {
    if (k0) __syncthreads();
    gl2lds16(aP0 + k0, lA0);
    gl2lds16(aP1 + k0, lA1);
    gl2lds16(bP0 + k0, lB0);
    gl2lds16(bP1 + k0, lB1);
    __syncthreads();
    bf16x8 af[4], bv[4];
#pragma unroll
    for (int i = 0; i < 4; ++i)
      af[i] = *(const bf16x8*)(As + (wm + i * 16 + llo) * 32 + lhi * 8);
#pragma unroll
    for (int j = 0; j < 4; ++j)
      bv[j] = *(const bf16x8*)(Bs + (wn + j * 16 + llo) * 32 + lhi * 8);
#pragma unroll
    for (int i = 0; i < 4; ++i)
#pragma unroll
      for (int j = 0; j < 4; ++j)
        acc[i][j] = __builtin_amdgcn_mfma_f32_16x16x32_bf16(af[i], bv[j], acc[i][j], 0, 0, 0);
  }
}

// ---------- transpose fp32 [R][C] -> bf16 [C][R], 64x64 tiles ----------
__global__ __launch_bounds__(256) void transpose_kernel(
    const float* __restrict__ in, bf16* __restrict__ out,
    int R, int C, long long inZ, long long outZ)
{
  __shared__ float tile[64][65];
  const long long zi = (long long)blockIdx.z * inZ;
  const long long zo = (long long)blockIdx.z * outZ;
  const int r0 = blockIdx.y * 64, c0 = blockIdx.x * 64;
  const int tid = threadIdx.x;
  const int tr = tid >> 4;
  const int tc = (tid & 15) * 4;
#pragma unroll
  for (int it = 0; it < 4; ++it) {
    int r = it * 16 + tr;
    float4 v = *(const float4*)(in + zi + (size_t)(r0 + r) * C + c0 + tc);
    tile[r][tc] = v.x; tile[r][tc + 1] = v.y; tile[r][tc + 2] = v.z; tile[r][tc + 3] = v.w;
  }
  __syncthreads();
#pragma unroll
  for (int it = 0; it < 4; ++it) {
    int c = it * 16 + tr;
    bf16x4 ov;
    ov[0] = (bf16)tile[tc + 0][c];
    ov[1] = (bf16)tile[tc + 1][c];
    ov[2] = (bf16)tile[tc + 2][c];
    ov[3] = (bf16)tile[tc + 3][c];
    *(bf16x4*)(out + zo + (size_t)(c0 + c) * R + r0 + tc) = ov;
  }
}

__global__ __launch_bounds__(256) void concat_bias(
    const float* __restrict__ bq, const float* __restrict__ bk,
    const float* __restrict__ bv, float* __restrict__ out)
{
  int i = blockIdx.x * 256 + threadIdx.x;
  if (i < 2048) out[i] = bq[i];
  else if (i < 4096) out[i] = bk[i - 2048];
  else if (i < 6144) out[i] = bv[i - 4096];
}

// ---------- router: logits, softmax, top-2, bucket scatter; fuses x->bf16 ----------
__global__ __launch_bounds__(256) void router_kernel(
    const float* __restrict__ x, const float* __restrict__ rw,
    const float* __restrict__ rb, bf16* __restrict__ xb,
    int* __restrict__ cnt, int* __restrict__ btok, float* __restrict__ bgate)
{
  const int tid = threadIdx.x, lane = tid & 63, wave = tid >> 6;
  const int tokBase = blockIdx.x * 16 + wave * 4;
  float acc[4][16];
#pragma unroll
  for (int t = 0; t < 4; ++t)
#pragma unroll
    for (int e = 0; e < 16; ++e) acc[t][e] = 0.f;

#pragma unroll 1
  for (int c = 0; c < 8; ++c) {
    const int f = c * 256 + lane * 4;
    float xv[4][4];
#pragma unroll
    for (int t = 0; t < 4; ++t) {
      float4 v = *(const float4*)(x + (size_t)(tokBase + t) * FDIM + f);
      xv[t][0] = v.x; xv[t][1] = v.y; xv[t][2] = v.z; xv[t][3] = v.w;
      bf16x4 b; b[0] = (bf16)v.x; b[1] = (bf16)v.y; b[2] = (bf16)v.z; b[3] = (bf16)v.w;
      *(bf16x4*)(xb + (size_t)(tokBase + t) * FDIM + f) = b;
    }
#pragma unroll
    for (int ff = 0; ff < 4; ++ff) {
      const float* rwr = rw + (size_t)(f + ff) * 16;
      float4 r0 = *(const float4*)(rwr);
      float4 r1 = *(const float4*)(rwr + 4);
      float4 r2 = *(const float4*)(rwr + 8);
      float4 r3 = *(const float4*)(rwr + 12);
      float rr[16] = {r0.x, r0.y, r0.z, r0.w, r1.x, r1.y, r1.z, r1.w,
                      r2.x, r2.y, r2.z, r2.w, r3.x, r3.y, r3.z, r3.w};
#pragma unroll
      for (int t = 0; t < 4; ++t) {
        float xs = xv[t][ff];
#pragma unroll
        for (int e = 0; e < 16; ++e) acc[t][e] = fmaf(xs, rr[e], acc[t][e]);
      }
    }
  }
#pragma unroll
  for (int t = 0; t < 4; ++t)
#pragma unroll
    for (int e = 0; e < 16; ++e) {
      float v = acc[t][e];
      v += __shfl_xor(v, 32); v += __shfl_xor(v, 16); v += __shfl_xor(v, 8);
      v += __shfl_xor(v, 4);  v += __shfl_xor(v, 2);  v += __shfl_xor(v, 1);
      acc[t][e] = v;
    }
  if (lane < 4) {
    const int tok = tokBase + lane;
    float lg[16];
#pragma unroll
    for (int e = 0; e < 16; ++e) lg[e] = acc[lane][e] + rb[e];
    float mx = lg[0];
#pragma unroll
    for (int e = 1; e < 16; ++e) mx = fmaxf(mx, lg[e]);
    float p[16], s = 0.f;
#pragma unroll
    for (int e = 0; e < 16; ++e) { p[e] = __expf(lg[e] - mx); s += p[e]; }
    const float inv = 1.f / s;
    int e0 = 0;
#pragma unroll
    for (int e = 1; e < 16; ++e) if (lg[e] > lg[e0]) e0 = e;
    int e1 = (e0 == 0) ? 1 : 0;
#pragma unroll
    for (int e = 0; e < 16; ++e) { if (e != e0 && lg[e] > lg[e1]) e1 = e; }
    const float g0 = p[e0] * inv, g1 = p[e1] * inv;
    int s0 = atomicAdd(cnt + e0, 1);
    btok[e0 * BSTRIDE + s0] = tok; bgate[e0 * BSTRIDE + s0] = g0;
    int s1 = atomicAdd(cnt + e1, 1);
    btok[e1 * BSTRIDE + s1] = tok; bgate[e1 * BSTRIDE + s1] = g1;
  }
}

// ---------- pad buckets to x128, build tile map + pass boundaries ----------
__global__ void finalize_buckets(const int* __restrict__ cnt, int* __restrict__ btok,
                                 float* __restrict__ bgate, int2* __restrict__ tmap,
                                 int* __restrict__ ntl3)
{
  __shared__ int tilesS[16];
  const int tid = threadIdx.x;
  if (tid < 16) tilesS[tid] = (cnt[tid] + 127) >> 7;
  __syncthreads();
  for (int e = 0; e < 16; ++e) {
    int c = cnt[e], end = tilesS[e] * 128;
    for (int i = c + tid; i < end; i += 256) {
      btok[e * BSTRIDE + i] = 0;
      bgate[e * BSTRIDE + i] = 0.f;
    }
  }
  if (tid == 0) {
    int s = 0, sA = 0;
    for (int e = 0; e < 16; ++e) {
      for (int m = 0; m < tilesS[e]; ++m) { tmap[s] = make_int2(e, m * 128); ++s; }
      if (e == 7) sA = s;
    }
    ntl3[0] = 0; ntl3[1] = sA; ntl3[2] = s;
  }
}

// ---------- gathered expert GEMM: relu(x@We + be) * gate -> atomicAdd moe32 ----------
// ewt holds a HALF of the experts: weight base = ewt + (e - e0) * 2048*2048.
// Tile range for this pass: [ntl3[passIdx], ntl3[passIdx+1]).
__global__ __launch_bounds__(256) void expert_gemm(
    const bf16* __restrict__ xb, const bf16* __restrict__ ewt,
    const float* __restrict__ eb, const int* __restrict__ btok,
    const float* __restrict__ bgate, const int2* __restrict__ tmap,
    const int* __restrict__ ntl3, int passIdx, int e0glob,
    float* __restrict__ moe32)
{
  __shared__ __align__(16) bf16 As[4096];
  __shared__ __align__(16) bf16 Bs[4096];
  __shared__ int   tokS[128];
  __shared__ float gateS[128];
  const int tstart = ntl3[passIdx], tend = ntl3[passIdx + 1];
  const int t = tstart + blockIdx.y;
  if (t >= tend) return;
  const int2 mp = tmap[t];
  const int e = mp.x, rowStart = mp.y;
  const int nBase = blockIdx.x * 128;
  const int tid = threadIdx.x;
  const int bbase = e * BSTRIDE + rowStart;
  if (tid < 128) {
    tokS[tid]  = btok[bbase + tid];
    gateS[tid] = bgate[bbase + tid];
  }
  const int rr0 = tid >> 2, rr1 = 64 + rr0;
  const int ch = (tid & 3) * 8;
  const int t0 = btok[bbase + rr0];
  const int t1 = btok[bbase + rr1];
  const bf16* aP0 = xb + (size_t)t0 * FDIM + ch;
  const bf16* aP1 = xb + (size_t)t1 * FDIM + ch;
  const bf16* Bb = ewt + ((size_t)(e - e0glob) << 22);
  const bf16* bP0 = Bb + (size_t)(nBase + rr0) * FDIM + ch;
  const bf16* bP1 = Bb + (size_t)(nBase + rr1) * FDIM + ch;

  f32x4 acc[4][4];
  const f32x4 zero = {0.f, 0.f, 0.f, 0.f};
#pragma unroll
  for (int i = 0; i < 4; ++i)
#pragma unroll
    for (int j = 0; j < 4; ++j) acc[i][j] = zero;

  gemm_core(aP0, aP1, bP0, bP1, FDIM, As, Bs, acc);

  const int lane = tid & 63, wave = tid >> 6;
  const int wm = (wave >> 1) * 64, wn = (wave & 1) * 64;
  const int lhi = lane >> 4, llo = lane & 15;
#pragma unroll
  for (int i = 0; i < 4; ++i) {
#pragma unroll
    for (int r = 0; r < 4; ++r) {
      const int rl = wm + i * 16 + lhi * 4 + r;
      const int tok = tokS[rl];
      const float g = gateS[rl];
      if (g != 0.f) {
#pragma unroll
        for (int j = 0; j < 4; ++j) {
          const int col = nBase + wn + j * 16 + llo;
          float v = acc[i][j][r] + eb[e * UDIM + col];
          v = fmaxf(v, 0.f);
          atomicAdd(moe32 + (size_t)tok * UDIM + col, v * g);
        }
      }
    }
  }
}

// ---------- generic GEMM + bias, A [M][K] bf16, Bt [N][K] bf16 ----------
template <typename OutT>
__global__ __launch_bounds__(256) void gemm_bias(
    const bf16* __restrict__ A, const bf16* __restrict__ Bt,
    const float* __restrict__ bias, OutT* __restrict__ C,
    int M, int N, int Kdim)
{
  __shared__ __align__(16) bf16 As[4096];
  __shared__ __align__(16) bf16 Bs[4096];
  const int mBase = blockIdx.y * 128, nBase = blockIdx.x * 128;
  const int tid = threadIdx.x;
  const int rr0 = tid >> 2, rr1 = 64 + rr0;
  const int ch = (tid & 3) * 8;
  const bf16* aP0 = A + (size_t)(mBase + rr0) * Kdim + ch;
  const bf16* aP1 = A + (size_t)(mBase + rr1) * Kdim + ch;
  const bf16* bP0 = Bt + (size_t)(nBase + rr0) * Kdim + ch;
  const bf16* bP1 = Bt + (size_t)(nBase + rr1) * Kdim + ch;

  f32x4 acc[4][4];
  const f32x4 zero = {0.f, 0.f, 0.f, 0.f};
#pragma unroll
  for (int i = 0; i < 4; ++i)
#pragma unroll
    for (int j = 0; j < 4; ++j) acc[i][j] = zero;

  gemm_core(aP0, aP1, bP0, bP1, Kdim, As, Bs, acc);

  const int lane = tid & 63, wave = tid >> 6;
  const int wm = (wave >> 1) * 64, wn = (wave & 1) * 64;
  const int lhi = lane >> 4, llo = lane & 15;
#pragma unroll
  for (int i = 0; i < 4; ++i) {
#pragma unroll
    for (int r = 0; r < 4; ++r) {
      const int row = mBase + wm + i * 16 + lhi * 4 + r;
#pragma unroll
      for (int j = 0; j < 4; ++j) {
        const int col = nBase + wn + j * 16 + llo;
        C[(size_t)row * N + col] = (OutT)(acc[i][j][r] + bias[col]);
      }
    }
  }
}

__global__ __launch_bounds__(256) void f32_to_bf16_vec(
    const float* __restrict__ in, bf16* __restrict__ out, int n4)
{
  int i = blockIdx.x * 256 + threadIdx.x;
  if (i >= n4) return;
  float4 v = ((const float4*)in)[i];
  bf16x4 b; b[0] = (bf16)v.x; b[1] = (bf16)v.y; b[2] = (bf16)v.z; b[3] = (bf16)v.w;
  ((bf16x4*)out)[i] = b;
}

// ---------- per-token MLA: scores, softmax over 16 heads, attn*v ----------
__global__ __launch_bounds__(256) void attn_kernel(
    const bf16* __restrict__ qkv, bf16* __restrict__ aout)
{
  const int lane = threadIdx.x & 63, wave = threadIdx.x >> 6;
  const int tok = blockIdx.x * 4 + wave;
  const bf16* base = qkv + (size_t)tok * (3 * DMODEL);
  const int h = lane >> 2, part = lane & 3;
  const int off = h * 128 + part * 32;
  float dot = 0.f;
#pragma unroll
  for (int c = 0; c < 4; ++c) {
    bf16x8 qv = *(const bf16x8*)(base + off + c * 8);
    bf16x8 kv = *(const bf16x8*)(base + DMODEL + off + c * 8);
#pragma unroll
    for (int u = 0; u < 8; ++u) dot += (float)qv[u] * (float)kv[u];
  }
  dot += __shfl_xor(dot, 1);
  dot += __shfl_xor(dot, 2);
  const float score = dot * 0.08838834764831845f;  // 1/sqrt(128)
  float sc[16];
#pragma unroll
  for (int e = 0; e < 16; ++e) sc[e] = __shfl(score, e * 4);
  float mx = sc[0];
#pragma unroll
  for (int e = 1; e < 16; ++e) mx = fmaxf(mx, sc[e]);
  float sum = 0.f, mex = 0.f;
#pragma unroll
  for (int e = 0; e < 16; ++e) {
    float ex = __expf(sc[e] - mx);
    sum += ex;
    mex = (e == h) ? ex : mex;
  }
  const float attn = mex / sum;
  bf16* op = aout + (size_t)tok * DMODEL + off;
#pragma unroll
  for (int c = 0; c < 4; ++c) {
    bf16x8 vv = *(const bf16x8*)(base + 2 * DMODEL + off + c * 8);
    bf16x8 ov;
#pragma unroll
    for (int u = 0; u < 8; ++u) ov[u] = (bf16)(attn * (float)vv[u]);
    *(bf16x8*)(op + c * 8) = ov;
  }
}

extern "C" void kernel_launch(void* const* d_in, const int* in_sizes, int n_in,
                              void* d_out, int out_size, void* d_ws, size_t ws_size,
                              hipStream_t stream) {
  const float* x   = (const float*)d_in[0];
  const float* rw  = (const float*)d_in[1];
  const float* rb  = (const float*)d_in[2];
  const float* ew  = (const float*)d_in[3];
  const float* eb  = (const float*)d_in[4];
  const float* wq  = (const float*)d_in[5];
  const float* bq  = (const float*)d_in[6];
  const float* wk  = (const float*)d_in[7];
  const float* bk  = (const float*)d_in[8];
  const float* wv  = (const float*)d_in[9];
  const float* bv  = (const float*)d_in[10];
  const float* wo_ = (const float*)d_in[11];
  const float* bo  = (const float*)d_in[12];
  float* out = (float*)d_out;

  uint8_t* ws = (uint8_t*)d_ws;
  // Static overlapped layout, peak ~193.2 MiB (was ~289 MiB: overflowed ws and
  // corrupted neighboring allocations -> post-timing divergence).
  //  [0,64M):    ewt half (experts e0..e0+7)  ->  moeb [0,32M)  ->  aout [0,32M)
  //  [64M,160M): moe32 [64M,128M)             ->  qkv  [64M,160M)
  //  [160M,192M):xb                           ->  qkvt [160M,184M) + wot [184M,192M)
  //  [192M,...): misc (bqkv, cnt, ntl3, tmap, btok, bgate)
  bf16*  ewt   = (bf16*)(ws);
  bf16*  moeb  = (bf16*)(ws);
  bf16*  aout  = (bf16*)(ws);
  float* moe32 = (float*)(ws + 67108864);
  bf16*  qkv   = (bf16*)(ws + 67108864);
  bf16*  xb    = (bf16*)(ws + 167772160);
  bf16*  qkvt  = (bf16*)(ws + 167772160);
  bf16*  wot   = (bf16*)(ws + 167772160 + 25165824);
  uint8_t* misc = ws + 201326592;
  float* bqkv  = (float*)(misc);            misc += 24576;
  int*   cnt   = (int*)(misc);              misc += 256;
  int*   ntl3  = (int*)(misc);              misc += 256;
  int2*  tmap  = (int2*)(misc);             misc += 2048;
  int*   btok  = (int*)(misc);              misc += 532480;
  float* bgate = (float*)(misc);            misc += 532480;

  hipMemsetAsync(moe32, 0, 67108864, stream);
  hipMemsetAsync(cnt, 0, 64, stream);

  // experts 0..7 -> ewt (bf16, [e][U][F])
  transpose_kernel<<<dim3(32, 32, 8), 256, 0, stream>>>(ew, ewt, FDIM, UDIM, 4194304LL, 4194304LL);
  router_kernel<<<512, 256, 0, stream>>>(x, rw, rb, xb, cnt, btok, bgate);
  finalize_buckets<<<1, 256, 0, stream>>>(cnt, btok, bgate, tmap, ntl3);
  expert_gemm<<<dim3(16, 136), 256, 0, stream>>>(xb, ewt, eb, btok, bgate, tmap, ntl3, 0, 0, moe32);
  // experts 8..15 into the same 64MB buffer
  transpose_kernel<<<dim3(32, 32, 8), 256, 0, stream>>>(ew + (size_t)8 * 4194304, ewt, FDIM, UDIM, 4194304LL, 4194304LL);
  expert_gemm<<<dim3(16, 136), 256, 0, stream>>>(xb, ewt, eb, btok, bgate, tmap, ntl3, 1, 8, moe32);

  // moe32 -> bf16 (ewt dead; moeb at ws+0)
  f32_to_bf16_vec<<<16384, 256, 0, stream>>>(moe32, moeb, 4194304);

  // xb dead now: transpose qkv/wo weights into its region
  transpose_kernel<<<dim3(32, 32, 1), 256, 0, stream>>>(wq, qkvt,            UDIM, DMODEL, 0, 0);
  transpose_kernel<<<dim3(32, 32, 1), 256, 0, stream>>>(wk, qkvt + 4194304,  UDIM, DMODEL, 0, 0);
  transpose_kernel<<<dim3(32, 32, 1), 256, 0, stream>>>(wv, qkvt + 8388608,  UDIM, DMODEL, 0, 0);
  transpose_kernel<<<dim3(32, 32, 1), 256, 0, stream>>>(wo_, wot, DMODEL, DMODEL, 0, 0);
  concat_bias<<<24, 256, 0, stream>>>(bq, bk, bv, bqkv);

  // fused QKV GEMM: [8192 x 6144 x 2048] (moe32 dead; qkv at ws+64M)
  gemm_bias<bf16><<<dim3(48, 64), 256, 0, stream>>>(moeb, qkvt, bqkv, qkv, BTOK, 3 * DMODEL, UDIM);
  attn_kernel<<<2048, 256, 0, stream>>>(qkv, aout);
  // output projection: [8192 x 2048 x 2048] + bo -> fp32 d_out
  gemm_bias<float><<<dim3(16, 64), 256, 0, stream>>>(aout, wot, bo, out, BTOK, DMODEL, 2048);
}